// Round 1
// baseline (271.802 us; speedup 1.0000x reference)
//
#include <hip/hip_runtime.h>
#include <hip/hip_bf16.h>
#include <stdint.h>

// Problem constants (B=4096, V=512, H=64)
#define BB 4096
#define VV 512
#define HH 64

typedef short bf16x8 __attribute__((ext_vector_type(8)));
typedef float floatx4 __attribute__((ext_vector_type(4)));
typedef unsigned short ushort8 __attribute__((ext_vector_type(8)));

typedef const __attribute__((address_space(1))) void g_void;
typedef __attribute__((address_space(3))) void l_void;

__device__ __forceinline__ void gload_lds16(const void* g, void* l) {
    __builtin_amdgcn_global_load_lds((g_void*)g, (l_void*)l, 16, 0, 0);
}

__device__ __forceinline__ unsigned short f2bf_rne(float f) {
    unsigned int u = __float_as_uint(f);
    u += 0x7FFFu + ((u >> 16) & 1u);   // round-to-nearest-even
    return (unsigned short)(u >> 16);
}

// ---------------------------------------------------------------- adj only
__global__ __launch_bounds__(256) void adj_kernel(const float* __restrict__ logits,
                                                  float* __restrict__ adj_out) {
    int idx = blockIdx.x * 256 + threadIdx.x;
    int v = idx >> 9, u = idx & (VV - 1);
    adj_out[idx] = (logits[idx] > 0.0f && v != u) ? 1.0f : 0.0f;
}

// ---------------------------------------------------------------- fused prep
// blocks [0, 4096): W1[i][v][h]*adj[v,i] -> bf16 W1t[i][h][v]  (B^T layout)
// blocks [4096, 5120): adj output + X -> plain row-major bf16 Xb[B][V]
__global__ __launch_bounds__(256) void prep_fused_kernel(
        const float* __restrict__ X, const float* __restrict__ logits,
        const float* __restrict__ W1, float* __restrict__ adj_out,
        unsigned short* __restrict__ Xb, unsigned short* __restrict__ W1t) {
    __shared__ float tile[64][65];   // stride 65: transpose-read conflict-free
    __shared__ float maskv[64];
    int bx = blockIdx.x;
    int t  = threadIdx.x;
    if (bx < 4096) {
        int i  = bx >> 3;
        int v0 = (bx & 7) << 6;
        if (t < 64) {
            int v = v0 + t;
            maskv[t] = (logits[(size_t)v * VV + i] > 0.0f && v != i) ? 1.0f : 0.0f;
        }
        // float4 global loads; scalar LDS writes at stride 65 (2-way, free).
        const float4* src4 = (const float4*)(W1 + ((size_t)i * VV + v0) * HH);
        #pragma unroll
        for (int jj = 0; jj < 4; ++jj) {
            int c  = jj * 256 + t;         // float4 index in [0, 4096)
            int vr = c >> 4, h4 = c & 15;
            float4 w = src4[c];
            tile[vr][h4 * 4 + 0] = w.x;
            tile[vr][h4 * 4 + 1] = w.y;
            tile[vr][h4 * 4 + 2] = w.z;
            tile[vr][h4 * 4 + 3] = w.w;
        }
        __syncthreads();
        unsigned short* dst = W1t + (size_t)i * (HH * VV) + v0;
        #pragma unroll
        for (int j = 0; j < 2; ++j) {
            int c = j * 256 + t;
            int h = c >> 3;
            int vr0 = (c & 7) * 8;
            ushort8 o;
            #pragma unroll
            for (int r = 0; r < 8; ++r)
                o[r] = f2bf_rne(tile[vr0 + r][h] * maskv[vr0 + r]);
            *(ushort8*)&dst[(size_t)h * VV + vr0] = o;
        }
    } else {
        int idx = (bx - 4096) * 256 + t;           // [0, 262144)
        {   // adj: sigmoid(x) > 0.5  <=>  x > 0 ; zero diagonal
            int v = idx >> 9, u = idx & (VV - 1);
            adj_out[idx] = (logits[idx] > 0.0f && v != u) ? 1.0f : 0.0f;
        }
        {   // X -> bf16, plain row-major (layouts are both linear: 8 elems/thread)
            const float4* s4 = (const float4*)(X + (size_t)idx * 8);
            float4 a = s4[0], b = s4[1];
            ushort8 o;
            o[0] = f2bf_rne(a.x); o[1] = f2bf_rne(a.y);
            o[2] = f2bf_rne(a.z); o[3] = f2bf_rne(a.w);
            o[4] = f2bf_rne(b.x); o[5] = f2bf_rne(b.y);
            o[6] = f2bf_rne(b.z); o[7] = f2bf_rne(b.w);
            *(ushort8*)(Xb + (size_t)idx * 8) = o;
        }
    }
}

// ---------------------------------------------------------------- main GEMM
// 256x256-tile 8-phase-style schedule (T2+T3+T4+T5): 4 i's fused along N
// (they share A = X exactly), BM=256, BK=32, 8 waves (2M x 4N), 512 thr.
// LDS: 3-buffer ring per operand (3x16KB A + 3x16KB B = 96KB + Po 4KB)
//   -> race-free counted-vmcnt pipeline: during tile t we stage tile t+2
//      into buf (t+2)%3, which was last READ at tile t-1 (barrier-separated).
//      Tile boundary: s_waitcnt vmcnt(4) (tile t+1 landed, t+2's 4 loads
//      still in flight) -- never drain-0 in the loop (T4).
// T2: pre-swizzled global source + swizzled ds_read, chunk ^= (row>>1)&3:
//      conflict-free per lane-octet (8 distinct 16B slots per octet).
// Block mapping: XCD-chunked (bx&7 = XCD), m-major within chunk -> per-XCD
//      W1t working set = 16 i-groups x 256KB = 4MB (~L2), Xb fetched ~once/m.
__global__ __launch_bounds__(512, 2) void dag_gemm_kernel(
        const unsigned short* __restrict__ Xb,    // [B][V] bf16
        const unsigned short* __restrict__ W1t,   // [V][H][V] bf16 (masked, B^T)
        const float* __restrict__ b1,             // [V][H]
        const float* __restrict__ W2,             // [V][H]
        const float* __restrict__ b2,             // [V]
        float* __restrict__ outT)                 // [V][B] transposed output
{
    __shared__ __align__(16) unsigned short As[3 * 8192];   // 3 x [256 rows][32 k]
    __shared__ __align__(16) unsigned short Bs[3 * 8192];   // 3 x [256 n  ][32 k]
    __shared__ float Po[1024];                              // [4 i][256 rows]

    const int tid  = threadIdx.x;
    const int wave = tid >> 6;
    const int lane = tid & 63;
    const int ln   = lane & 15;
    const int quad = lane >> 4;
    const int wr   = wave >> 2;      // M half: rows wr*128..+127
    const int wn   = wave & 3;       // N group: i = i0 + wn, h = 0..63

    const int bx   = blockIdx.x;                       // 2048 blocks
    const int ig   = ((bx & 7) << 4) + ((bx >> 3) & 15);
    const int m    = bx >> 7;
    const int i0   = ig << 2;
    const int row0 = m << 8;

    // ---- staging descriptors: thread handles chunks c=tid and c=512+tid
    //      (chunk c: row r=c>>2, 16B slot j=c&3; source slot = j ^ ((r>>1)&3))
    const int rA = tid >> 2, jc = tid & 3, sw = (tid >> 3) & 3;
    const unsigned short* srcA = Xb + (size_t)(row0 + rA) * VV + ((jc ^ sw) << 3);
    const unsigned short* srcB = W1t + (size_t)(i0 + (rA >> 6)) * (HH * VV)
                                     + (size_t)(rA & 63) * VV + ((jc ^ sw) << 3);
    char* dstA = (char*)As + (tid << 4);
    char* dstB = (char*)Bs + (tid << 4);

    auto stageA = [&](int t, int buf) {   // +65536 elems: rows +128 (swz invariant)
        gload_lds16(srcA + t * 32,         dstA + (buf << 14));
        gload_lds16(srcA + t * 32 + 65536, dstA + (buf << 14) + 8192);
    };
    auto stageB = [&](int t, int buf) {   // +65536 elems: n +128 -> i +2
        gload_lds16(srcB + t * 32,         dstB + (buf << 14));
        gload_lds16(srcB + t * 32 + 65536, dstB + (buf << 14) + 8192);
    };

    // ---- fragment read offsets (bytes); row stride 64B, slot swizzled
    const int slot = (quad ^ ((ln >> 1) & 3)) << 4;
    const int aoff = (((wr << 7) + ln) << 6) + slot;   // + mt*1024
    const int boff = (((wn << 6) + ln) << 6) + slot;   // + nt*1024

    floatx4 acc[8][4];
    #pragma unroll
    for (int a = 0; a < 8; ++a)
        #pragma unroll
        for (int b = 0; b < 4; ++b)
            acc[a][b] = (floatx4){0.f, 0.f, 0.f, 0.f};

    // ---- prologue: stage tiles 0,1; wait tile 0 (leave tile 1's 4 in flight)
    stageA(0, 0); stageB(0, 0); stageA(1, 1); stageB(1, 1);
    asm volatile("s_waitcnt vmcnt(4)" ::: "memory");
    asm volatile("s_barrier" ::: "memory");

    bf16x8 af[8], bq[4];
    #pragma unroll
    for (int t = 0; t < 16; ++t) {
        const int buf  = t % 3;
        const int nbuf = (t + 2) % 3;
        const char* ab = (const char*)As + (buf << 14);
        const char* bb = (const char*)Bs + (buf << 14);

        // ---------------- phase 0: read A0-3,B0-3 | stage A(t+2) | MFMA mt0-3
        #pragma unroll
        for (int mt = 0; mt < 4; ++mt)
            af[mt] = *(const bf16x8*)(ab + aoff + (mt << 10));
        #pragma unroll
        for (int nt = 0; nt < 4; ++nt)
            bq[nt] = *(const bf16x8*)(bb + boff + (nt << 10));
        if (t <= 13) stageA(t + 2, nbuf);
        asm volatile("s_barrier" ::: "memory");
        asm volatile("s_waitcnt lgkmcnt(0)" ::: "memory");
        __builtin_amdgcn_sched_barrier(0);
        __builtin_amdgcn_s_setprio(1);
        #pragma unroll
        for (int mt = 0; mt < 4; ++mt)
            #pragma unroll
            for (int nt = 0; nt < 4; ++nt)
                acc[mt][nt] = __builtin_amdgcn_mfma_f32_16x16x32_bf16(
                    af[mt], bq[nt], acc[mt][nt], 0, 0, 0);
        __builtin_amdgcn_s_setprio(0);
        asm volatile("s_barrier" ::: "memory");

        // ---------------- phase 1: read A4-7 | stage B(t+2) | MFMA mt4-7
        #pragma unroll
        for (int mt = 4; mt < 8; ++mt)
            af[mt] = *(const bf16x8*)(ab + aoff + (mt << 10));
        if (t <= 13) stageB(t + 2, nbuf);
        asm volatile("s_barrier" ::: "memory");
        asm volatile("s_waitcnt lgkmcnt(0)" ::: "memory");
        __builtin_amdgcn_sched_barrier(0);
        __builtin_amdgcn_s_setprio(1);
        #pragma unroll
        for (int mt = 4; mt < 8; ++mt)
            #pragma unroll
            for (int nt = 0; nt < 4; ++nt)
                acc[mt][nt] = __builtin_amdgcn_mfma_f32_16x16x32_bf16(
                    af[mt], bq[nt], acc[mt][nt], 0, 0, 0);
        __builtin_amdgcn_s_setprio(0);

        // ---------------- tile boundary: counted vmcnt (T4), then barrier
        if (t < 15) {
            if (t <= 13) asm volatile("s_waitcnt vmcnt(4)" ::: "memory");
            else         asm volatile("s_waitcnt vmcnt(0)" ::: "memory");
            asm volatile("s_barrier" ::: "memory");
        }
    }

    // ---- fused epilogue: relu(acc + b1) . W2 + b2 (each wave owns one i)
    const int i = i0 + wn;
    float b1v[4], w2v[4];
    #pragma unroll
    for (int nt = 0; nt < 4; ++nt) {
        b1v[nt] = b1[i * HH + nt * 16 + ln];
        w2v[nt] = W2[i * HH + nt * 16 + ln];
    }
    const float b2i = b2[i];
    #pragma unroll
    for (int mt = 0; mt < 8; ++mt) {
        #pragma unroll
        for (int r = 0; r < 4; ++r) {
            float p = 0.f;
            #pragma unroll
            for (int nt = 0; nt < 4; ++nt) {
                float hv = acc[mt][nt][r] + b1v[nt];   // C/D: row=quad*4+r, col=nt*16+ln
                hv = hv > 0.f ? hv : 0.f;
                p += hv * w2v[nt];
            }
            p += __shfl_xor(p, 8);
            p += __shfl_xor(p, 4);
            p += __shfl_xor(p, 2);
            p += __shfl_xor(p, 1);
            if (ln == 0)
                Po[(wn << 8) + (wr << 7) + mt * 16 + (quad << 2) + r] = p + b2i;
        }
    }
    __syncthreads();
    {
        int il = tid >> 7, rr = (tid & 127) << 1;
        *(float2*)&outT[(size_t)(i0 + il) * BB + row0 + rr] =
            *(const float2*)&Po[(il << 8) + rr];
    }
}

// ------------------------------------------- outT[V][B] -> out[B][V] transpose
__global__ __launch_bounds__(256) void transpose_kernel(const float* __restrict__ outT,
                                                        float* __restrict__ out) {
    __shared__ float tile[64][65];
    int i0 = (blockIdx.x & 7) * 64;
    int r0 = (blockIdx.x >> 3) * 64;
    int t  = threadIdx.x;
    #pragma unroll
    for (int j = 0; j < 16; ++j) {
        int idx = j * 256 + t;
        int ii = idx >> 6, rr = idx & 63;
        tile[ii][rr] = outT[(size_t)(i0 + ii) * BB + r0 + rr];
    }
    __syncthreads();
    #pragma unroll
    for (int j = 0; j < 16; ++j) {
        int idx = j * 256 + t;
        int rr = idx >> 6, ii = idx & 63;
        out[(size_t)(r0 + rr) * VV + i0 + ii] = tile[ii][rr];
    }
}

// ----------------------------- fallback (no workspace): fp32 vector path
__global__ __launch_bounds__(256) void fallback_kernel(
        const float* __restrict__ X, const float* __restrict__ logits,
        const float* __restrict__ W1, const float* __restrict__ b1,
        const float* __restrict__ W2, const float* __restrict__ b2,
        float* __restrict__ out) {
    __shared__ float Wc[128][64];
    int i   = blockIdx.x & (VV - 1);
    int row = (blockIdx.x >> 9) * 256 + threadIdx.x;
    float acc[64];
    #pragma unroll
    for (int h = 0; h < 64; ++h) acc[h] = 0.f;
    for (int v0 = 0; v0 < VV; v0 += 128) {
        __syncthreads();
        for (int j = 0; j < 32; ++j) {
            int idx = j * 256 + threadIdx.x;
            int vr = idx >> 6, h = idx & 63;
            int v = v0 + vr;
            float m = (logits[(size_t)v * VV + i] > 0.f && v != i) ? 1.f : 0.f;
            Wc[vr][h] = W1[((size_t)i * VV + v) * HH + h] * m;
        }
        __syncthreads();
        for (int vr = 0; vr < 128; ++vr) {
            float xv = X[(size_t)row * VV + v0 + vr];
            #pragma unroll
            for (int h = 0; h < 64; ++h) acc[h] += xv * Wc[vr][h];
        }
    }
    float p = b2[i];
    #pragma unroll
    for (int h = 0; h < 64; ++h) {
        float hv = acc[h] + b1[i * HH + h];
        p += (hv > 0.f ? hv : 0.f) * W2[i * HH + h];
    }
    out[(size_t)row * VV + i] = p;
}

extern "C" void kernel_launch(void* const* d_in, const int* in_sizes, int n_in,
                              void* d_out, int out_size, void* d_ws, size_t ws_size,
                              hipStream_t stream) {
    const float* X      = (const float*)d_in[0];
    const float* logits = (const float*)d_in[1];
    const float* W1     = (const float*)d_in[2];
    const float* b1     = (const float*)d_in[3];
    const float* W2     = (const float*)d_in[4];
    const float* b2     = (const float*)d_in[5];

    float* out     = (float*)d_out;                       // reconstructed [B][V]
    float* adj_out = out + (size_t)BB * VV;               // adj [V][V]

    const size_t xb_bytes   = (size_t)BB * VV * 2;        // 4 MB
    const size_t w1t_bytes  = (size_t)VV * HH * VV * 2;   // 32 MB
    const size_t outt_bytes = (size_t)BB * VV * 4;        // 8 MB
    const size_t need = xb_bytes + w1t_bytes + outt_bytes;

    if (ws_size >= need) {
        unsigned short* Xb   = (unsigned short*)d_ws;
        unsigned short* W1t  = (unsigned short*)((char*)d_ws + xb_bytes);
        float*          outT = (float*)((char*)d_ws + xb_bytes + w1t_bytes);
        hipLaunchKernelGGL(prep_fused_kernel, dim3(5120), dim3(256), 0, stream,
                           X, logits, W1, adj_out, Xb, W1t);
        hipLaunchKernelGGL(dag_gemm_kernel, dim3(2048), dim3(512), 0, stream,
                           Xb, W1t, b1, W2, b2, outT);
        hipLaunchKernelGGL(transpose_kernel, dim3((BB / 64) * (VV / 64)), dim3(256), 0, stream,
                           outT, out);
    } else {
        hipLaunchKernelGGL(adj_kernel, dim3((VV * VV) / 256), dim3(256), 0, stream,
                           logits, adj_out);
        hipLaunchKernelGGL(fallback_kernel, dim3(VV * (BB / 256)), dim3(256), 0, stream,
                           X, logits, W1, b1, W2, b2, out);
    }
}

// Round 2
// 256.744 us; speedup vs baseline: 1.0587x; 1.0587x over previous
//
#include <hip/hip_runtime.h>
#include <hip/hip_bf16.h>
#include <stdint.h>

// Problem constants (B=4096, V=512, H=64)
#define BB 4096
#define VV 512
#define HH 64

typedef short bf16x8 __attribute__((ext_vector_type(8)));
typedef float floatx4 __attribute__((ext_vector_type(4)));
typedef unsigned short ushort8 __attribute__((ext_vector_type(8)));

typedef const __attribute__((address_space(1))) void g_void;
typedef __attribute__((address_space(3))) void l_void;

__device__ __forceinline__ void gload_lds16(const void* g, void* l) {
    __builtin_amdgcn_global_load_lds((g_void*)g, (l_void*)l, 16, 0, 0);
}

__device__ __forceinline__ unsigned short f2bf_rne(float f) {
    unsigned int u = __float_as_uint(f);
    u += 0x7FFFu + ((u >> 16) & 1u);   // round-to-nearest-even
    return (unsigned short)(u >> 16);
}

// ---------------------------------------------------------------- adj only
__global__ __launch_bounds__(256) void adj_kernel(const float* __restrict__ logits,
                                                  float* __restrict__ adj_out) {
    int idx = blockIdx.x * 256 + threadIdx.x;
    int v = idx >> 9, u = idx & (VV - 1);
    adj_out[idx] = (logits[idx] > 0.0f && v != u) ? 1.0f : 0.0f;
}

// ---------------------------------------------------------------- fused prep
// blocks [0, 4096): W1[i][v][h]*adj[v,i] -> bf16 W1t[i][h][v]  (B^T layout)
// blocks [4096, 5120): adj output + X -> packed bf16 Xp
// Xp layout: [rb][ks][mt][lane][8]; lane=quad*16+ln holds
// X[rb*64+mt*16+ln][ks*32+quad*8..+7] => A-frag loads are coalesced 1 KB.
__global__ __launch_bounds__(256) void prep_fused_kernel(
        const float* __restrict__ X, const float* __restrict__ logits,
        const float* __restrict__ W1, float* __restrict__ adj_out,
        unsigned short* __restrict__ Xp, unsigned short* __restrict__ W1t) {
    __shared__ float tile[64][65];   // stride 65: transpose-read conflict-free
    __shared__ float maskv[64];
    int bx = blockIdx.x;
    int t  = threadIdx.x;
    if (bx < 4096) {
        int i  = bx >> 3;
        int v0 = (bx & 7) << 6;
        if (t < 64) {
            int v = v0 + t;
            maskv[t] = (logits[(size_t)v * VV + i] > 0.0f && v != i) ? 1.0f : 0.0f;
        }
        // float4 global loads; scalar LDS writes at stride 65 (2-way, free).
        const float4* src4 = (const float4*)(W1 + ((size_t)i * VV + v0) * HH);
        #pragma unroll
        for (int jj = 0; jj < 4; ++jj) {
            int c  = jj * 256 + t;         // float4 index in [0, 4096)
            int vr = c >> 4, h4 = c & 15;
            float4 w = src4[c];
            tile[vr][h4 * 4 + 0] = w.x;
            tile[vr][h4 * 4 + 1] = w.y;
            tile[vr][h4 * 4 + 2] = w.z;
            tile[vr][h4 * 4 + 3] = w.w;
        }
        __syncthreads();
        unsigned short* dst = W1t + (size_t)i * (HH * VV) + v0;
        #pragma unroll
        for (int j = 0; j < 2; ++j) {
            int c = j * 256 + t;
            int h = c >> 3;
            int vr0 = (c & 7) * 8;
            ushort8 o;
            #pragma unroll
            for (int r = 0; r < 8; ++r)
                o[r] = f2bf_rne(tile[vr0 + r][h] * maskv[vr0 + r]);
            *(ushort8*)&dst[(size_t)h * VV + vr0] = o;
        }
    } else {
        int idx = (bx - 4096) * 256 + t;           // [0, 262144)
        {   // adj: sigmoid(x) > 0.5  <=>  x > 0 ; zero diagonal
            int v = idx >> 9, u = idx & (VV - 1);
            adj_out[idx] = (logits[idx] > 0.0f && v != u) ? 1.0f : 0.0f;
        }
        {   // pack chunk idx (two float4 reads, one 16B store)
            int lane = idx & 63;
            int mt   = (idx >> 6) & 3;
            int ks   = (idx >> 8) & 15;
            int rb   = idx >> 12;
            int row  = rb * 64 + mt * 16 + (lane & 15);
            int k0   = ks * 32 + (lane >> 4) * 8;
            const float4* s4 = (const float4*)(X + (size_t)row * VV + k0);
            float4 a = s4[0], b = s4[1];
            ushort8 o;
            o[0] = f2bf_rne(a.x); o[1] = f2bf_rne(a.y);
            o[2] = f2bf_rne(a.z); o[3] = f2bf_rne(a.w);
            o[4] = f2bf_rne(b.x); o[5] = f2bf_rne(b.y);
            o[6] = f2bf_rne(b.z); o[7] = f2bf_rne(b.w);
            *(ushort8*)(Xp + (size_t)idx * 8) = o;
        }
    }
}

// ---------------------------------------------------------------- main GEMM
// R0's proven structure (3 blocks/CU, 12 waves/CU, 33 KB LDS, mid-block K
// re-stage covered by the other resident blocks) with two deltas:
//   1. XCD-chunked bijective block remap: xcd = bx&7 owns i in
//      [xcd*64, xcd*64+64), row-groups inner. Per-XCD steady state:
//      6 concurrent i's x 64 KB B = 384 KB + Xp 4 MB -> L2-resident,
//      vs i-major order that replicated every W1t row into all 8 L2s.
//   2. Direct out[row][i] epilogue store (transpose kernel deleted).
//      The 16 writers of each 64 B out-line share an XCD and are
//      time-adjacent (i-window slides by 1) -> L2 write-merges full lines.
__global__ __launch_bounds__(256, 3) void dag_gemm_kernel(
        const unsigned short* __restrict__ Xp,    // packed A frags
        const unsigned short* __restrict__ W1t,   // [V][H][V] bf16 (masked, B^T)
        const float* __restrict__ b1,             // [V][H]
        const float* __restrict__ W2,             // [V][H]
        const float* __restrict__ b2,             // [V]
        float* __restrict__ out)                  // [B][V] final output
{
    __shared__ __align__(16) unsigned short Ws[16384];   // 32 KB: [h][s2], s2 in [0,32)
    __shared__ float Po[256];                            // epilogue gather

    const int t    = threadIdx.x;
    const int wave = t >> 6;
    const int lane = t & 63;
    const int ln   = lane & 15;
    const int quad = lane >> 4;

    // XCD-chunked bijective remap (8192 % 8 == 0): each XCD gets a
    // contiguous 64-i slice; 16 consecutive local blocks share W1t row i.
    const int bx    = blockIdx.x;         // 8192 blocks
    const int local = bx >> 3;            // [0, 1024) within this XCD
    const int i     = ((bx & 7) << 6) + (local >> 4);
    const int row0  = (local & 15) << 8;

    // B-frag fetch: pos = in-half chunk (k/8 units, [0,32)) of row h=nt*16+ln
    auto ldb = [&](int pos, int nt) -> bf16x8 {
        return *(const bf16x8*)&Ws[(nt * 16 + ln) * 256 + ((pos ^ (ln & 7)) * 8)];
    };

    // wave's packed A stream: 64 KB contiguous, frag(ks,mt) at +(ks*4+mt)*512
    const unsigned short* abase =
        Xp + (size_t)((row0 >> 6) + wave) * (64 * VV) + lane * 8;

    // ---- issue first 3 K-steps of A prefetch (oldest in vmem queue)
    bf16x8 af[4][4];
    #pragma unroll
    for (int s = 0; s < 3; ++s)
        #pragma unroll
        for (int mt = 0; mt < 4; ++mt)
            af[s][mt] = *(const bf16x8*)(abase + (s * 4 + mt) * 512);

    // ---- stage W1t k-half0 (32 KB): lds addr = c*16 (lane-contiguous ✓)
    const unsigned short* wbase = W1t + (size_t)i * (HH * VV);
    #pragma unroll
    for (int j = 0; j < 8; ++j) {
        int c = j * 256 + t;              // [0, 2048)
        int h = c >> 5, s2 = c & 31;
        gload_lds16(wbase + (size_t)h * VV + (size_t)(s2 ^ (h & 7)) * 8,
                    (char*)Ws + c * 16);
    }
    __syncthreads();   // drains: half0 staged + af[0..2] complete

    floatx4 acc[4][4];
    #pragma unroll
    for (int a = 0; a < 4; ++a)
        #pragma unroll
        for (int b = 0; b < 4; ++b)
            acc[a][b] = (floatx4){0.f, 0.f, 0.f, 0.f};

    bf16x8 bq[2][4];
    #pragma unroll
    for (int nt = 0; nt < 4; ++nt)
        bq[0][nt] = ldb(quad, nt);

    // ---- K-steps 0..7 (k in [0,256): half0)
    #pragma unroll
    for (int kk = 0; kk < 8; ++kk) {
        #pragma unroll
        for (int mt = 0; mt < 4; ++mt)     // A prefetch for step kk+3
            af[(kk + 3) & 3][mt] =
                *(const bf16x8*)(abase + ((kk + 3) * 4 + mt) * 512);
        if (kk < 7) {                      // B prefetch for step kk+1 (half0)
            #pragma unroll
            for (int nt = 0; nt < 4; ++nt)
                bq[(kk + 1) & 1][nt] = ldb((kk + 1) * 4 + quad, nt);
        }
        #pragma unroll
        for (int mt = 0; mt < 4; ++mt)
            #pragma unroll
            for (int nt = 0; nt < 4; ++nt)
                acc[mt][nt] = __builtin_amdgcn_mfma_f32_16x16x32_bf16(
                    af[kk & 3][mt], bq[kk & 1][nt], acc[mt][nt], 0, 0, 0);
    }

    __syncthreads();   // all waves done READING half0

    // ---- re-stage half1 (k in [256,512)) into the SAME buffer
    #pragma unroll
    for (int j = 0; j < 8; ++j) {
        int c = j * 256 + t;
        int h = c >> 5, s2 = c & 31;
        gload_lds16(wbase + (size_t)h * VV + (size_t)(32 + (s2 ^ (h & 7))) * 8,
                    (char*)Ws + c * 16);
    }
    __syncthreads();   // drains half1 (covered by other resident blocks)

    // B frags for step 8 (pos 0 of new half)
    #pragma unroll
    for (int nt = 0; nt < 4; ++nt)
        bq[0][nt] = ldb(quad, nt);

    // ---- K-steps 8..15 (k in [256,512): half1)
    #pragma unroll
    for (int kk = 8; kk < 16; ++kk) {
        if (kk < 13) {
            #pragma unroll
            for (int mt = 0; mt < 4; ++mt)
                af[(kk + 3) & 3][mt] =
                    *(const bf16x8*)(abase + ((kk + 3) * 4 + mt) * 512);
        }
        if (kk < 15) {
            #pragma unroll
            for (int nt = 0; nt < 4; ++nt)
                bq[(kk + 1) & 1][nt] = ldb(((kk + 1) - 8) * 4 + quad, nt);
        }
        #pragma unroll
        for (int mt = 0; mt < 4; ++mt)
            #pragma unroll
            for (int nt = 0; nt < 4; ++nt)
                acc[mt][nt] = __builtin_amdgcn_mfma_f32_16x16x32_bf16(
                    af[kk & 3][mt], bq[kk & 1][nt], acc[mt][nt], 0, 0, 0);
    }

    // ---- fused epilogue: relu(acc + b1) . W2 + b2, fp32; Po gather is
    //      strictly intra-wave -> no barrier needed before the store.
    float b1v[4], w2v[4];
    #pragma unroll
    for (int nt = 0; nt < 4; ++nt) {
        b1v[nt] = b1[i * HH + nt * 16 + ln];
        w2v[nt] = W2[i * HH + nt * 16 + ln];
    }
    const float b2i = b2[i];
    #pragma unroll
    for (int mt = 0; mt < 4; ++mt) {
        #pragma unroll
        for (int r = 0; r < 4; ++r) {
            float p = 0.f;
            #pragma unroll
            for (int nt = 0; nt < 4; ++nt) {
                float hv = acc[mt][nt][r] + b1v[nt];   // C/D: row=quad*4+r, col=nt*16+ln
                hv = hv > 0.f ? hv : 0.f;
                p += hv * w2v[nt];
            }
            p += __shfl_xor(p, 8);
            p += __shfl_xor(p, 4);
            p += __shfl_xor(p, 2);
            p += __shfl_xor(p, 1);
            if (ln == 0)
                Po[wave * 64 + mt * 16 + quad * 4 + r] = p + b2i;
        }
    }
    // direct transposed store: one instr/wave, 64 scattered 4B lanes;
    // L2 merges (all 16 writers of a line are same-XCD, time-adjacent).
    out[(size_t)(row0 + wave * 64 + lane) * VV + i] = Po[wave * 64 + lane];
}

// ----------------------------- fallback (no workspace): fp32 vector path
__global__ __launch_bounds__(256) void fallback_kernel(
        const float* __restrict__ X, const float* __restrict__ logits,
        const float* __restrict__ W1, const float* __restrict__ b1,
        const float* __restrict__ W2, const float* __restrict__ b2,
        float* __restrict__ out) {
    __shared__ float Wc[128][64];
    int i   = blockIdx.x & (VV - 1);
    int row = (blockIdx.x >> 9) * 256 + threadIdx.x;
    float acc[64];
    #pragma unroll
    for (int h = 0; h < 64; ++h) acc[h] = 0.f;
    for (int v0 = 0; v0 < VV; v0 += 128) {
        __syncthreads();
        for (int j = 0; j < 32; ++j) {
            int idx = j * 256 + threadIdx.x;
            int vr = idx >> 6, h = idx & 63;
            int v = v0 + vr;
            float m = (logits[(size_t)v * VV + i] > 0.f && v != i) ? 1.f : 0.f;
            Wc[vr][h] = W1[((size_t)i * VV + v) * HH + h] * m;
        }
        __syncthreads();
        for (int vr = 0; vr < 128; ++vr) {
            float xv = X[(size_t)row * VV + v0 + vr];
            #pragma unroll
            for (int h = 0; h < 64; ++h) acc[h] += xv * Wc[vr][h];
        }
    }
    float p = b2[i];
    #pragma unroll
    for (int h = 0; h < 64; ++h) {
        float hv = acc[h] + b1[i * HH + h];
        p += (hv > 0.f ? hv : 0.f) * W2[i * HH + h];
    }
    out[(size_t)row * VV + i] = p;
}

extern "C" void kernel_launch(void* const* d_in, const int* in_sizes, int n_in,
                              void* d_out, int out_size, void* d_ws, size_t ws_size,
                              hipStream_t stream) {
    const float* X      = (const float*)d_in[0];
    const float* logits = (const float*)d_in[1];
    const float* W1     = (const float*)d_in[2];
    const float* b1     = (const float*)d_in[3];
    const float* W2     = (const float*)d_in[4];
    const float* b2     = (const float*)d_in[5];

    float* out     = (float*)d_out;                       // reconstructed [B][V]
    float* adj_out = out + (size_t)BB * VV;               // adj [V][V]

    const size_t xp_bytes  = (size_t)BB * VV * 2;         // 4 MB
    const size_t w1t_bytes = (size_t)VV * HH * VV * 2;    // 32 MB
    const size_t need = xp_bytes + w1t_bytes;

    if (ws_size >= need) {
        unsigned short* Xp  = (unsigned short*)d_ws;
        unsigned short* W1t = (unsigned short*)((char*)d_ws + xp_bytes);
        hipLaunchKernelGGL(prep_fused_kernel, dim3(5120), dim3(256), 0, stream,
                           X, logits, W1, adj_out, Xp, W1t);
        hipLaunchKernelGGL(dag_gemm_kernel, dim3(8192), dim3(256), 0, stream,
                           Xp, W1t, b1, W2, b2, out);
    } else {
        hipLaunchKernelGGL(adj_kernel, dim3((VV * VV) / 256), dim3(256), 0, stream,
                           logits, adj_out);
        hipLaunchKernelGGL(fallback_kernel, dim3(VV * (BB / 256)), dim3(256), 0, stream,
                           X, logits, W1, b1, W2, b2, out);
    }
}

// Round 3
// 244.566 us; speedup vs baseline: 1.1114x; 1.0498x over previous
//
#include <hip/hip_runtime.h>
#include <hip/hip_bf16.h>
#include <stdint.h>

// Problem constants (B=4096, V=512, H=64)
#define BB 4096
#define VV 512
#define HH 64

typedef short bf16x8 __attribute__((ext_vector_type(8)));
typedef float floatx4 __attribute__((ext_vector_type(4)));
typedef unsigned short ushort8 __attribute__((ext_vector_type(8)));

typedef const __attribute__((address_space(1))) void g_void;
typedef __attribute__((address_space(3))) void l_void;

__device__ __forceinline__ void gload_lds16(const void* g, void* l) {
    __builtin_amdgcn_global_load_lds((g_void*)g, (l_void*)l, 16, 0, 0);
}

__device__ __forceinline__ unsigned short f2bf_rne(float f) {
    unsigned int u = __float_as_uint(f);
    u += 0x7FFFu + ((u >> 16) & 1u);   // round-to-nearest-even
    return (unsigned short)(u >> 16);
}

// ---------------------------------------------------------------- adj only
__global__ __launch_bounds__(256) void adj_kernel(const float* __restrict__ logits,
                                                  float* __restrict__ adj_out) {
    int idx = blockIdx.x * 256 + threadIdx.x;
    int v = idx >> 9, u = idx & (VV - 1);
    adj_out[idx] = (logits[idx] > 0.0f && v != u) ? 1.0f : 0.0f;
}

// ---------------------------------------------------------------- fused prep
// blocks [0, 4096): W1[i][v][h]*adj[v,i] -> bf16 W1t[i][h][v]  (B^T layout)
// blocks [4096, 5120): adj output + X -> packed bf16 Xp
// Xp layout: [rb][ks][mt][lane][8]; lane=quad*16+ln holds
// X[rb*64+mt*16+ln][ks*32+quad*8..+7] => A-frag loads are coalesced 1 KB.
__global__ __launch_bounds__(256) void prep_fused_kernel(
        const float* __restrict__ X, const float* __restrict__ logits,
        const float* __restrict__ W1, float* __restrict__ adj_out,
        unsigned short* __restrict__ Xp, unsigned short* __restrict__ W1t) {
    __shared__ float tile[64][65];   // stride 65: transpose-read conflict-free
    __shared__ float maskv[64];
    int bx = blockIdx.x;
    int t  = threadIdx.x;
    if (bx < 4096) {
        int i  = bx >> 3;
        int v0 = (bx & 7) << 6;
        if (t < 64) {
            int v = v0 + t;
            maskv[t] = (logits[(size_t)v * VV + i] > 0.0f && v != i) ? 1.0f : 0.0f;
        }
        // float4 global loads; scalar LDS writes at stride 65 (2-way, free).
        const float4* src4 = (const float4*)(W1 + ((size_t)i * VV + v0) * HH);
        #pragma unroll
        for (int jj = 0; jj < 4; ++jj) {
            int c  = jj * 256 + t;         // float4 index in [0, 4096)
            int vr = c >> 4, h4 = c & 15;
            float4 w = src4[c];
            tile[vr][h4 * 4 + 0] = w.x;
            tile[vr][h4 * 4 + 1] = w.y;
            tile[vr][h4 * 4 + 2] = w.z;
            tile[vr][h4 * 4 + 3] = w.w;
        }
        __syncthreads();
        unsigned short* dst = W1t + (size_t)i * (HH * VV) + v0;
        #pragma unroll
        for (int j = 0; j < 2; ++j) {
            int c = j * 256 + t;
            int h = c >> 3;
            int vr0 = (c & 7) * 8;
            ushort8 o;
            #pragma unroll
            for (int r = 0; r < 8; ++r)
                o[r] = f2bf_rne(tile[vr0 + r][h] * maskv[vr0 + r]);
            *(ushort8*)&dst[(size_t)h * VV + vr0] = o;
        }
    } else {
        int idx = (bx - 4096) * 256 + t;           // [0, 262144)
        {   // adj: sigmoid(x) > 0.5  <=>  x > 0 ; zero diagonal
            int v = idx >> 9, u = idx & (VV - 1);
            adj_out[idx] = (logits[idx] > 0.0f && v != u) ? 1.0f : 0.0f;
        }
        {   // pack chunk idx (two float4 reads, one 16B store)
            int lane = idx & 63;
            int mt   = (idx >> 6) & 3;
            int ks   = (idx >> 8) & 15;
            int rb   = idx >> 12;
            int row  = rb * 64 + mt * 16 + (lane & 15);
            int k0   = ks * 32 + (lane >> 4) * 8;
            const float4* s4 = (const float4*)(X + (size_t)row * VV + k0);
            float4 a = s4[0], b = s4[1];
            ushort8 o;
            o[0] = f2bf_rne(a.x); o[1] = f2bf_rne(a.y);
            o[2] = f2bf_rne(a.z); o[3] = f2bf_rne(a.w);
            o[4] = f2bf_rne(b.x); o[5] = f2bf_rne(b.y);
            o[6] = f2bf_rne(b.z); o[7] = f2bf_rne(b.w);
            *(ushort8*)(Xp + (size_t)idx * 8) = o;
        }
    }
}

// ---------------------------------------------------------------- main GEMM
// R0 skeleton + IFUSE=2: each block computes 256 rows x TWO adjacent i's,
// reusing every A-fragment register for both i's MFMAs.
//   A (Xp) L2 traffic: 2 GB -> 1 GB (the modeled dominant term; GEMM was
//   neither MFMA- (~17 us floor) nor HBM-bound -- it rode the L2/latency).
//   B traffic unchanged (each W1t row still staged by 16 row-blocks).
// Natural i-major dispatch kept (R2's XCD remap RAISED fetch 46% -- the
// real dispatch mapping beat the %8 heuristic; don't fight it).
// Occupancy: 2 blocks/CU (acc 2x -> ~230 VGPR under (256,2) cap 256; LDS
// 66 KB: 2 x 32 KB half-K for both i's + Po). Mid-block drain frequency
// per MFMA is HALVED vs R0 (2 drains / 512 MFMA per wave), compensating
// the single covering block.
// Direct out[row][i] store kept (transpose kernel deleted): writers of an
// out line are bx strided by 16 -> time-adjacent, L2 write-merges; R2
// measured the inflation at only ~9 MB (~1.5 us).
__global__ __launch_bounds__(256, 2) void dag_gemm_kernel(
        const unsigned short* __restrict__ Xp,    // packed A frags
        const unsigned short* __restrict__ W1t,   // [V][H][V] bf16 (masked, B^T)
        const float* __restrict__ b1,             // [V][H]
        const float* __restrict__ W2,             // [V][H]
        const float* __restrict__ b2,             // [V]
        float* __restrict__ out)                  // [B][V] final output
{
    __shared__ __align__(16) unsigned short Ws[2][16384];  // 64 KB: [i][h][s2]
    __shared__ float Po[2][256];                           // epilogue gather

    const int t    = threadIdx.x;
    const int wave = t >> 6;
    const int lane = t & 63;
    const int ln   = lane & 15;
    const int quad = lane >> 4;

    const int bx   = blockIdx.x;          // 4096 blocks, i-pair-major
    const int i0   = (bx >> 4) << 1;      // 16 consecutive blocks share i-pair
    const int row0 = (bx & 15) << 8;

    // B-frag fetch: pos = in-half chunk (k/8 units, [0,32)) of row h=nt*16+ln
    auto ldb = [&](int ii, int pos, int nt) -> bf16x8 {
        return *(const bf16x8*)&Ws[ii][(nt * 16 + ln) * 256 + ((pos ^ (ln & 7)) * 8)];
    };

    // wave's packed A stream: 64 KB contiguous, frag(ks,mt) at +(ks*4+mt)*512
    const unsigned short* abase =
        Xp + (size_t)((row0 >> 6) + wave) * (64 * VV) + lane * 8;

    // ---- A prefetch for step 0 (oldest in vmem queue)
    bf16x8 af[2][4];
    #pragma unroll
    for (int mt = 0; mt < 4; ++mt)
        af[0][mt] = *(const bf16x8*)(abase + mt * 512);

    // ---- stage W1t k-half (32 KB per i): lds addr = c*16 (lane-contiguous)
    const unsigned short* wb0 = W1t + (size_t)i0 * (HH * VV);
    const unsigned short* wb1 = W1t + (size_t)(i0 + 1) * (HH * VV);
    auto stage = [&](int kb) {            // kb = 0 (half0) or 32 (half1), in k/8 units
        #pragma unroll
        for (int j = 0; j < 8; ++j) {
            int c = j * 256 + t;          // [0, 2048)
            int h = c >> 5, s2 = c & 31;
            size_t off = (size_t)h * VV + (size_t)(kb + (s2 ^ (h & 7))) * 8;
            gload_lds16(wb0 + off, (char*)&Ws[0][0] + c * 16);
            gload_lds16(wb1 + off, (char*)&Ws[1][0] + c * 16);
        }
    };
    stage(0);
    __syncthreads();   // drains: half0 staged (both i) + af[0] complete

    floatx4 acc[2][4][4];
    #pragma unroll
    for (int ii = 0; ii < 2; ++ii)
        #pragma unroll
        for (int a = 0; a < 4; ++a)
            #pragma unroll
            for (int b = 0; b < 4; ++b)
                acc[ii][a][b] = (floatx4){0.f, 0.f, 0.f, 0.f};

    bf16x8 bq[2][2][4];                   // [step parity][ii][nt]
    #pragma unroll
    for (int ii = 0; ii < 2; ++ii)
        #pragma unroll
        for (int nt = 0; nt < 4; ++nt)
            bq[0][ii][nt] = ldb(ii, quad, nt);

    // ---- K-steps 0..7 (k in [0,256): half0)
    #pragma unroll
    for (int kk = 0; kk < 8; ++kk) {
        #pragma unroll
        for (int mt = 0; mt < 4; ++mt)     // A prefetch for step kk+1
            af[(kk + 1) & 1][mt] =
                *(const bf16x8*)(abase + ((kk + 1) * 4 + mt) * 512);
        if (kk < 7) {                      // B prefetch for step kk+1 (half0)
            #pragma unroll
            for (int ii = 0; ii < 2; ++ii)
                #pragma unroll
                for (int nt = 0; nt < 4; ++nt)
                    bq[(kk + 1) & 1][ii][nt] = ldb(ii, (kk + 1) * 4 + quad, nt);
        }
        #pragma unroll
        for (int ii = 0; ii < 2; ++ii)
            #pragma unroll
            for (int mt = 0; mt < 4; ++mt)
                #pragma unroll
                for (int nt = 0; nt < 4; ++nt)
                    acc[ii][mt][nt] = __builtin_amdgcn_mfma_f32_16x16x32_bf16(
                        af[kk & 1][mt], bq[kk & 1][ii][nt], acc[ii][mt][nt], 0, 0, 0);
    }

    __syncthreads();   // all waves done READING half0 (both i)

    // ---- re-stage half1 (k in [256,512)) into the SAME buffers
    stage(32);
    __syncthreads();   // drains half1 (covered by the other resident block)

    // B frags for step 8 (pos 0 of new half)
    #pragma unroll
    for (int ii = 0; ii < 2; ++ii)
        #pragma unroll
        for (int nt = 0; nt < 4; ++nt)
            bq[0][ii][nt] = ldb(ii, quad, nt);

    // ---- K-steps 8..15 (k in [256,512): half1)
    #pragma unroll
    for (int kk = 8; kk < 16; ++kk) {
        if (kk < 15) {
            #pragma unroll
            for (int mt = 0; mt < 4; ++mt)
                af[(kk + 1) & 1][mt] =
                    *(const bf16x8*)(abase + ((kk + 1) * 4 + mt) * 512);
            #pragma unroll
            for (int ii = 0; ii < 2; ++ii)
                #pragma unroll
                for (int nt = 0; nt < 4; ++nt)
                    bq[(kk + 1) & 1][ii][nt] = ldb(ii, ((kk + 1) - 8) * 4 + quad, nt);
        }
        #pragma unroll
        for (int ii = 0; ii < 2; ++ii)
            #pragma unroll
            for (int mt = 0; mt < 4; ++mt)
                #pragma unroll
                for (int nt = 0; nt < 4; ++nt)
                    acc[ii][mt][nt] = __builtin_amdgcn_mfma_f32_16x16x32_bf16(
                        af[kk & 1][mt], bq[kk & 1][ii][nt], acc[ii][mt][nt], 0, 0, 0);
    }

    // ---- fused epilogue: relu(acc + b1) . W2 + b2, fp32; Po gather is
    //      strictly intra-wave -> no barrier needed before the store.
    float b1v[2][4], w2v[2][4], b2i[2];
    #pragma unroll
    for (int ii = 0; ii < 2; ++ii) {
        #pragma unroll
        for (int nt = 0; nt < 4; ++nt) {
            b1v[ii][nt] = b1[(i0 + ii) * HH + nt * 16 + ln];
            w2v[ii][nt] = W2[(i0 + ii) * HH + nt * 16 + ln];
        }
        b2i[ii] = b2[i0 + ii];
    }
    #pragma unroll
    for (int ii = 0; ii < 2; ++ii) {
        #pragma unroll
        for (int mt = 0; mt < 4; ++mt) {
            #pragma unroll
            for (int r = 0; r < 4; ++r) {
                float p = 0.f;
                #pragma unroll
                for (int nt = 0; nt < 4; ++nt) {
                    float hv = acc[ii][mt][nt][r] + b1v[ii][nt];   // row=quad*4+r, col=nt*16+ln
                    hv = hv > 0.f ? hv : 0.f;
                    p += hv * w2v[ii][nt];
                }
                p += __shfl_xor(p, 8);
                p += __shfl_xor(p, 4);
                p += __shfl_xor(p, 2);
                p += __shfl_xor(p, 1);
                if (ln == 0)
                    Po[ii][wave * 64 + mt * 16 + quad * 4 + r] = p + b2i[ii];
            }
        }
    }
    // direct transposed store: two instrs/lane; writers of each 64 B out
    // line are bx-stride-16 time-adjacent blocks -> L2 write-merges.
    const int row = row0 + wave * 64 + lane;
    out[(size_t)row * VV + i0]     = Po[0][wave * 64 + lane];
    out[(size_t)row * VV + i0 + 1] = Po[1][wave * 64 + lane];
}

// ----------------------------- fallback (no workspace): fp32 vector path
__global__ __launch_bounds__(256) void fallback_kernel(
        const float* __restrict__ X, const float* __restrict__ logits,
        const float* __restrict__ W1, const float* __restrict__ b1,
        const float* __restrict__ W2, const float* __restrict__ b2,
        float* __restrict__ out) {
    __shared__ float Wc[128][64];
    int i   = blockIdx.x & (VV - 1);
    int row = (blockIdx.x >> 9) * 256 + threadIdx.x;
    float acc[64];
    #pragma unroll
    for (int h = 0; h < 64; ++h) acc[h] = 0.f;
    for (int v0 = 0; v0 < VV; v0 += 128) {
        __syncthreads();
        for (int j = 0; j < 32; ++j) {
            int idx = j * 256 + threadIdx.x;
            int vr = idx >> 6, h = idx & 63;
            int v = v0 + vr;
            float m = (logits[(size_t)v * VV + i] > 0.f && v != i) ? 1.f : 0.f;
            Wc[vr][h] = W1[((size_t)i * VV + v) * HH + h] * m;
        }
        __syncthreads();
        for (int vr = 0; vr < 128; ++vr) {
            float xv = X[(size_t)row * VV + v0 + vr];
            #pragma unroll
            for (int h = 0; h < 64; ++h) acc[h] += xv * Wc[vr][h];
        }
    }
    float p = b2[i];
    #pragma unroll
    for (int h = 0; h < 64; ++h) {
        float hv = acc[h] + b1[i * HH + h];
        p += (hv > 0.f ? hv : 0.f) * W2[i * HH + h];
    }
    out[(size_t)row * VV + i] = p;
}

extern "C" void kernel_launch(void* const* d_in, const int* in_sizes, int n_in,
                              void* d_out, int out_size, void* d_ws, size_t ws_size,
                              hipStream_t stream) {
    const float* X      = (const float*)d_in[0];
    const float* logits = (const float*)d_in[1];
    const float* W1     = (const float*)d_in[2];
    const float* b1     = (const float*)d_in[3];
    const float* W2     = (const float*)d_in[4];
    const float* b2     = (const float*)d_in[5];

    float* out     = (float*)d_out;                       // reconstructed [B][V]
    float* adj_out = out + (size_t)BB * VV;               // adj [V][V]

    const size_t xp_bytes  = (size_t)BB * VV * 2;         // 4 MB
    const size_t w1t_bytes = (size_t)VV * HH * VV * 2;    // 32 MB
    const size_t need = xp_bytes + w1t_bytes;

    if (ws_size >= need) {
        unsigned short* Xp  = (unsigned short*)d_ws;
        unsigned short* W1t = (unsigned short*)((char*)d_ws + xp_bytes);
        hipLaunchKernelGGL(prep_fused_kernel, dim3(5120), dim3(256), 0, stream,
                           X, logits, W1, adj_out, Xp, W1t);
        hipLaunchKernelGGL(dag_gemm_kernel, dim3(4096), dim3(256), 0, stream,
                           Xp, W1t, b1, W2, b2, out);
    } else {
        hipLaunchKernelGGL(adj_kernel, dim3((VV * VV) / 256), dim3(256), 0, stream,
                           logits, adj_out);
        hipLaunchKernelGGL(fallback_kernel, dim3(VV * (BB / 256)), dim3(256), 0, stream,
                           X, logits, W1, b1, W2, b2, out);
    }
}

// Round 4
// 242.388 us; speedup vs baseline: 1.1214x; 1.0090x over previous
//
#include <hip/hip_runtime.h>
#include <hip/hip_bf16.h>
#include <stdint.h>

// Problem constants (B=4096, V=512, H=64)
#define BB 4096
#define VV 512
#define HH 64

typedef short bf16x8 __attribute__((ext_vector_type(8)));
typedef float floatx4 __attribute__((ext_vector_type(4)));
typedef unsigned short ushort8 __attribute__((ext_vector_type(8)));

typedef const __attribute__((address_space(1))) void g_void;
typedef __attribute__((address_space(3))) void l_void;

__device__ __forceinline__ void gload_lds16(const void* g, void* l) {
    __builtin_amdgcn_global_load_lds((g_void*)g, (l_void*)l, 16, 0, 0);
}

__device__ __forceinline__ unsigned short f2bf_rne(float f) {
    unsigned int u = __float_as_uint(f);
    u += 0x7FFFu + ((u >> 16) & 1u);   // round-to-nearest-even
    return (unsigned short)(u >> 16);
}

// ---------------------------------------------------------------- adj only
__global__ __launch_bounds__(256) void adj_kernel(const float* __restrict__ logits,
                                                  float* __restrict__ adj_out) {
    int idx = blockIdx.x * 256 + threadIdx.x;
    int v = idx >> 9, u = idx & (VV - 1);
    adj_out[idx] = (logits[idx] > 0.0f && v != u) ? 1.0f : 0.0f;
}

// ---------------------------------------------------------------- fused prep
// blocks [0, 4096): W1[i][v][h]*adj[v,i] -> bf16 W1t[i][h][v]  (B^T layout)
// blocks [4096, 5120): adj output + X -> packed bf16 Xp
// Xp layout: [rb][ks][mt][lane][8]; lane=quad*16+ln holds
// X[rb*64+mt*16+ln][ks*32+quad*8..+7] => A-frag loads are coalesced 1 KB.
__global__ __launch_bounds__(256) void prep_fused_kernel(
        const float* __restrict__ X, const float* __restrict__ logits,
        const float* __restrict__ W1, float* __restrict__ adj_out,
        unsigned short* __restrict__ Xp, unsigned short* __restrict__ W1t) {
    __shared__ float tile[64][65];   // stride 65: transpose-read conflict-free
    __shared__ float maskv[64];
    int bx = blockIdx.x;
    int t  = threadIdx.x;
    if (bx < 4096) {
        int i  = bx >> 3;
        int v0 = (bx & 7) << 6;
        if (t < 64) {
            int v = v0 + t;
            maskv[t] = (logits[(size_t)v * VV + i] > 0.0f && v != i) ? 1.0f : 0.0f;
        }
        // float4 global loads; scalar LDS writes at stride 65 (2-way, free).
        const float4* src4 = (const float4*)(W1 + ((size_t)i * VV + v0) * HH);
        #pragma unroll
        for (int jj = 0; jj < 4; ++jj) {
            int c  = jj * 256 + t;         // float4 index in [0, 4096)
            int vr = c >> 4, h4 = c & 15;
            float4 w = src4[c];
            tile[vr][h4 * 4 + 0] = w.x;
            tile[vr][h4 * 4 + 1] = w.y;
            tile[vr][h4 * 4 + 2] = w.z;
            tile[vr][h4 * 4 + 3] = w.w;
        }
        __syncthreads();
        unsigned short* dst = W1t + (size_t)i * (HH * VV) + v0;
        #pragma unroll
        for (int j = 0; j < 2; ++j) {
            int c = j * 256 + t;
            int h = c >> 3;
            int vr0 = (c & 7) * 8;
            ushort8 o;
            #pragma unroll
            for (int r = 0; r < 8; ++r)
                o[r] = f2bf_rne(tile[vr0 + r][h] * maskv[vr0 + r]);
            *(ushort8*)&dst[(size_t)h * VV + vr0] = o;
        }
    } else {
        int idx = (bx - 4096) * 256 + t;           // [0, 262144)
        {   // adj: sigmoid(x) > 0.5  <=>  x > 0 ; zero diagonal
            int v = idx >> 9, u = idx & (VV - 1);
            adj_out[idx] = (logits[idx] > 0.0f && v != u) ? 1.0f : 0.0f;
        }
        {   // pack chunk idx (two float4 reads, one 16B store)
            int lane = idx & 63;
            int mt   = (idx >> 6) & 3;
            int ks   = (idx >> 8) & 15;
            int rb   = idx >> 12;
            int row  = rb * 64 + mt * 16 + (lane & 15);
            int k0   = ks * 32 + (lane >> 4) * 8;
            const float4* s4 = (const float4*)(X + (size_t)row * VV + k0);
            float4 a = s4[0], b = s4[1];
            ushort8 o;
            o[0] = f2bf_rne(a.x); o[1] = f2bf_rne(a.y);
            o[2] = f2bf_rne(a.z); o[3] = f2bf_rne(a.w);
            o[4] = f2bf_rne(b.x); o[5] = f2bf_rne(b.y);
            o[6] = f2bf_rne(b.z); o[7] = f2bf_rne(b.w);
            *(ushort8*)(Xp + (size_t)idx * 8) = o;
        }
    }
}

// ---------------------------------------------------------------- main GEMM
// R3 geometry frozen (4096 blocks: 16 row-chunks x 256 i-pairs, IFUSE=2,
// 4 waves x 64 rows, same frags/swizzle/epilogue). K-loop restructured:
// BK=64 tiles (8 of them), 3-buffer LDS ring (3 x 16 KB = 2i x 8 KB),
// counted-vmcnt pipeline (T3+T4) -- NO vmcnt(0)/lgkmcnt(0) drain in loop.
//   tile t: read buf[t%3]; stage(t+2)->buf[(t+2)%3] issued YOUNGEST;
//   boundary: s_waitcnt vmcnt(12) (= this tile's A(8) + stage(t+2)(4)
//   still in flight; everything older -- incl. stage(t+1) -- forced done),
//   then raw s_barrier. Ring race-free: buf[(t+2)%3] last read at t-1,
//   barrier-separated. R1's failure causes fixed: LDS 49 KB (not 100) ->
//   2 blocks/CU kept ((256,2), ~126 arch VGPR + 128 acc, spill-free);
//   prefetch depth 2 tiles (~800 cy) covers L3 latency.
// vmcnt counting assumes NO scratch/spill VMEM ops -- tripwire: VGPR=256.
__global__ __launch_bounds__(256, 2) void dag_gemm_kernel(
        const unsigned short* __restrict__ Xp,    // packed A frags
        const unsigned short* __restrict__ W1t,   // [V][H][V] bf16 (masked, B^T)
        const float* __restrict__ b1,             // [V][H]
        const float* __restrict__ W2,             // [V][H]
        const float* __restrict__ b2,             // [V]
        float* __restrict__ out)                  // [B][V] final output
{
    __shared__ __align__(16) unsigned short Ws[3 * 8192];  // 48 KB ring
    __shared__ float Po[2][256];                           // epilogue gather

    const int tid  = threadIdx.x;
    const int wave = tid >> 6;
    const int lane = tid & 63;
    const int ln   = lane & 15;
    const int quad = lane >> 4;

    const int bx   = blockIdx.x;          // 4096 blocks, i-pair-major
    const int i0   = (bx >> 4) << 1;      // 16 consecutive blocks share i-pair
    const int row0 = (bx & 15) << 8;

    // ---- staging: tile tt covers v in [tt*64, tt*64+64), both i's.
    // c = j*256+tid: ii=c>>9, h=(c>>3)&63, s=c&7 (16B chunk in 128B row);
    // LDS dst = buf + c*16 (lane-contiguous, m104-safe); source pre-swizzled
    // s ^ (h&7) so the read-side XOR (same involution) sees natural data.
    const unsigned short* wb0 = W1t + (size_t)i0 * (HH * VV);
    auto stage = [&](int tt, int buf) {
        #pragma unroll
        for (int j = 0; j < 4; ++j) {
            int c = j * 256 + tid;        // [0, 1024)
            int ii = c >> 9, h = (c >> 3) & 63, s = c & 7;
            gload_lds16(wb0 + (size_t)ii * (HH * VV) + h * VV + tt * 64
                            + ((s ^ (h & 7)) * 8),
                        (char*)Ws + buf * 16384 + c * 16);
        }
    };

    // B-frag read: row h=nt*16+ln, in-tile 16B chunk pos = kstep*4+quad
    auto ldb = [&](const unsigned short* wb, int ii, int pos, int nt) -> bf16x8 {
        return *(const bf16x8*)&wb[ii * 4096 + (nt * 16 + ln) * 64
                                   + ((pos ^ (ln & 7)) * 8)];
    };

    // wave's packed A stream: frag(ks,mt) at +(ks*4+mt)*512 shorts (1 KB coalesced)
    const unsigned short* abase =
        Xp + (size_t)((row0 >> 6) + wave) * (64 * VV) + lane * 8;

    // ---- prologue: A ks=0, stage tiles 0,1; wait stage0 (stage1 in flight)
    bf16x8 af[2][4];
    #pragma unroll
    for (int mt = 0; mt < 4; ++mt)
        af[0][mt] = *(const bf16x8*)(abase + mt * 512);
    stage(0, 0);
    stage(1, 1);
    asm volatile("s_waitcnt vmcnt(4)" ::: "memory");
    asm volatile("s_barrier" ::: "memory");

    floatx4 acc[2][4][4];
    #pragma unroll
    for (int ii = 0; ii < 2; ++ii)
        #pragma unroll
        for (int a = 0; a < 4; ++a)
            #pragma unroll
            for (int b = 0; b < 4; ++b)
                acc[ii][a][b] = (floatx4){0.f, 0.f, 0.f, 0.f};

    bf16x8 bq[2][2][4];                   // [kstep][ii][nt]

    #pragma unroll
    for (int tt = 0; tt < 8; ++tt) {      // 8 K-tiles of 64
        const unsigned short* wb = Ws + (tt % 3) * 8192;

        // B frags, step 0 (exposed ~120cy, amortized across 8 waves/CU)
        #pragma unroll
        for (int ii = 0; ii < 2; ++ii)
            #pragma unroll
            for (int nt = 0; nt < 4; ++nt)
                bq[0][ii][nt] = ldb(wb, ii, quad, nt);
        // A prefetch ks=2tt+1 (odd parity)
        #pragma unroll
        for (int mt = 0; mt < 4; ++mt)
            af[1][mt] = *(const bf16x8*)(abase + ((2 * tt + 1) * 4 + mt) * 512);
        // B frags, step 1 (hidden under step-0 MFMAs)
        #pragma unroll
        for (int ii = 0; ii < 2; ++ii)
            #pragma unroll
            for (int nt = 0; nt < 4; ++nt)
                bq[1][ii][nt] = ldb(wb, ii, 4 + quad, nt);

        // MFMA step 0 (ks = 2tt)
        __builtin_amdgcn_s_setprio(1);
        #pragma unroll
        for (int ii = 0; ii < 2; ++ii)
            #pragma unroll
            for (int mt = 0; mt < 4; ++mt)
                #pragma unroll
                for (int nt = 0; nt < 4; ++nt)
                    acc[ii][mt][nt] = __builtin_amdgcn_mfma_f32_16x16x32_bf16(
                        af[0][mt], bq[0][ii][nt], acc[ii][mt][nt], 0, 0, 0);
        __builtin_amdgcn_s_setprio(0);

        // A prefetch ks=2tt+2 (even parity) for next tile's step 0
        if (tt < 7) {
            #pragma unroll
            for (int mt = 0; mt < 4; ++mt)
                af[0][mt] = *(const bf16x8*)(abase + ((2 * tt + 2) * 4 + mt) * 512);
        }

        // MFMA step 1 (ks = 2tt+1)
        __builtin_amdgcn_s_setprio(1);
        #pragma unroll
        for (int ii = 0; ii < 2; ++ii)
            #pragma unroll
            for (int mt = 0; mt < 4; ++mt)
                #pragma unroll
                for (int nt = 0; nt < 4; ++nt)
                    acc[ii][mt][nt] = __builtin_amdgcn_mfma_f32_16x16x32_bf16(
                        af[1][mt], bq[1][ii][nt], acc[ii][mt][nt], 0, 0, 0);
        __builtin_amdgcn_s_setprio(0);

        // stage tile tt+2, issued YOUNGEST so boundary wait keeps it in flight
        if (tt < 6) stage(tt + 2, (tt + 2) % 3);

        // boundary: counted vmcnt (never 0), light barrier
        if (tt < 7) {
            if (tt < 6) asm volatile("s_waitcnt vmcnt(12)" ::: "memory");
            else        asm volatile("s_waitcnt vmcnt(8)"  ::: "memory");
            asm volatile("s_barrier" ::: "memory");
        }
    }

    // ---- fused epilogue: relu(acc + b1) . W2 + b2, fp32; Po gather is
    //      strictly intra-wave -> no barrier needed before the store.
    float b1v[2][4], w2v[2][4], b2i[2];
    #pragma unroll
    for (int ii = 0; ii < 2; ++ii) {
        #pragma unroll
        for (int nt = 0; nt < 4; ++nt) {
            b1v[ii][nt] = b1[(i0 + ii) * HH + nt * 16 + ln];
            w2v[ii][nt] = W2[(i0 + ii) * HH + nt * 16 + ln];
        }
        b2i[ii] = b2[i0 + ii];
    }
    #pragma unroll
    for (int ii = 0; ii < 2; ++ii) {
        #pragma unroll
        for (int mt = 0; mt < 4; ++mt) {
            #pragma unroll
            for (int r = 0; r < 4; ++r) {
                float p = 0.f;
                #pragma unroll
                for (int nt = 0; nt < 4; ++nt) {
                    float hv = acc[ii][mt][nt][r] + b1v[ii][nt];   // row=quad*4+r, col=nt*16+ln
                    hv = hv > 0.f ? hv : 0.f;
                    p += hv * w2v[ii][nt];
                }
                p += __shfl_xor(p, 8);
                p += __shfl_xor(p, 4);
                p += __shfl_xor(p, 2);
                p += __shfl_xor(p, 1);
                if (ln == 0)
                    Po[ii][wave * 64 + mt * 16 + quad * 4 + r] = p + b2i[ii];
            }
        }
    }
    // direct transposed store: writers of each 64 B out line are
    // bx-stride-16 time-adjacent blocks -> L2 write-merges.
    const int row = row0 + wave * 64 + lane;
    out[(size_t)row * VV + i0]     = Po[0][wave * 64 + lane];
    out[(size_t)row * VV + i0 + 1] = Po[1][wave * 64 + lane];
}

// ----------------------------- fallback (no workspace): fp32 vector path
__global__ __launch_bounds__(256) void fallback_kernel(
        const float* __restrict__ X, const float* __restrict__ logits,
        const float* __restrict__ W1, const float* __restrict__ b1,
        const float* __restrict__ W2, const float* __restrict__ b2,
        float* __restrict__ out) {
    __shared__ float Wc[128][64];
    int i   = blockIdx.x & (VV - 1);
    int row = (blockIdx.x >> 9) * 256 + threadIdx.x;
    float acc[64];
    #pragma unroll
    for (int h = 0; h < 64; ++h) acc[h] = 0.f;
    for (int v0 = 0; v0 < VV; v0 += 128) {
        __syncthreads();
        for (int j = 0; j < 32; ++j) {
            int idx = j * 256 + threadIdx.x;
            int vr = idx >> 6, h = idx & 63;
            int v = v0 + vr;
            float m = (logits[(size_t)v * VV + i] > 0.f && v != i) ? 1.f : 0.f;
            Wc[vr][h] = W1[((size_t)i * VV + v) * HH + h] * m;
        }
        __syncthreads();
        for (int vr = 0; vr < 128; ++vr) {
            float xv = X[(size_t)row * VV + v0 + vr];
            #pragma unroll
            for (int h = 0; h < 64; ++h) acc[h] += xv * Wc[vr][h];
        }
    }
    float p = b2[i];
    #pragma unroll
    for (int h = 0; h < 64; ++h) {
        float hv = acc[h] + b1[i * HH + h];
        p += (hv > 0.f ? hv : 0.f) * W2[i * HH + h];
    }
    out[(size_t)row * VV + i] = p;
}

extern "C" void kernel_launch(void* const* d_in, const int* in_sizes, int n_in,
                              void* d_out, int out_size, void* d_ws, size_t ws_size,
                              hipStream_t stream) {
    const float* X      = (const float*)d_in[0];
    const float* logits = (const float*)d_in[1];
    const float* W1     = (const float*)d_in[2];
    const float* b1     = (const float*)d_in[3];
    const float* W2     = (const float*)d_in[4];
    const float* b2     = (const float*)d_in[5];

    float* out     = (float*)d_out;                       // reconstructed [B][V]
    float* adj_out = out + (size_t)BB * VV;               // adj [V][V]

    const size_t xp_bytes  = (size_t)BB * VV * 2;         // 4 MB
    const size_t w1t_bytes = (size_t)VV * HH * VV * 2;    // 32 MB
    const size_t need = xp_bytes + w1t_bytes;

    if (ws_size >= need) {
        unsigned short* Xp  = (unsigned short*)d_ws;
        unsigned short* W1t = (unsigned short*)((char*)d_ws + xp_bytes);
        hipLaunchKernelGGL(prep_fused_kernel, dim3(5120), dim3(256), 0, stream,
                           X, logits, W1, adj_out, Xp, W1t);
        hipLaunchKernelGGL(dag_gemm_kernel, dim3(4096), dim3(256), 0, stream,
                           Xp, W1t, b1, W2, b2, out);
    } else {
        hipLaunchKernelGGL(adj_kernel, dim3((VV * VV) / 256), dim3(256), 0, stream,
                           logits, adj_out);
        hipLaunchKernelGGL(fallback_kernel, dim3(VV * (BB / 256)), dim3(256), 0, stream,
                           X, logits, W1, b1, W2, b2, out);
    }
}

// Round 5
// 235.897 us; speedup vs baseline: 1.1522x; 1.0275x over previous
//
#include <hip/hip_runtime.h>
#include <hip/hip_bf16.h>
#include <stdint.h>

// Problem constants (B=4096, V=512, H=64)
#define BB 4096
#define VV 512
#define HH 64

typedef short bf16x8 __attribute__((ext_vector_type(8)));
typedef float floatx4 __attribute__((ext_vector_type(4)));
typedef unsigned short ushort8 __attribute__((ext_vector_type(8)));

typedef const __attribute__((address_space(1))) void g_void;
typedef __attribute__((address_space(3))) void l_void;

__device__ __forceinline__ void gload_lds16(const void* g, void* l) {
    __builtin_amdgcn_global_load_lds((g_void*)g, (l_void*)l, 16, 0, 0);
}

__device__ __forceinline__ unsigned short f2bf_rne(float f) {
    unsigned int u = __float_as_uint(f);
    u += 0x7FFFu + ((u >> 16) & 1u);   // round-to-nearest-even
    return (unsigned short)(u >> 16);
}

// ---------------------------------------------------------------- adj only
__global__ __launch_bounds__(256) void adj_kernel(const float* __restrict__ logits,
                                                  float* __restrict__ adj_out) {
    int idx = blockIdx.x * 256 + threadIdx.x;
    int v = idx >> 9, u = idx & (VV - 1);
    adj_out[idx] = (logits[idx] > 0.0f && v != u) ? 1.0f : 0.0f;
}

// ---------------------------------------------------------------- fused prep
// Rewritten for latency hiding + clean access patterns (prep measured ~4x
// its ~20 us roofline; GEMM-side counters ruled out the other kernels).
// blocks [0, 1024): (i, v-half) pairs -- W1[i][v][h]*adj[v,i] -> bf16
//   W1t[i][h][v].  4x work per block vs before, double-buffered LDS tile,
//   load(s+1) overlaps store(s); maskv loaded once per 256 v's.
// blocks [1024, 2048): adj output + X -> packed bf16 Xp.
//   Reads are now CONTIGUOUS (each wave reads linear 2 KB runs of X; the
//   old version did 2KB-strided 16B reads = 64 lines per 1 KB consumed);
//   the Xp-layout scatter moved to the write side (fire-and-forget).
// Xp layout preserved exactly: chunk (rb,ks,mt,lane) holds
//   X[rb*64+mt*16+(lane&15)][ks*32+(lane>>4)*8 ..+7].
__global__ __launch_bounds__(256) void prep_fused_kernel(
        const float* __restrict__ X, const float* __restrict__ logits,
        const float* __restrict__ W1, float* __restrict__ adj_out,
        unsigned short* __restrict__ Xp, unsigned short* __restrict__ W1t) {
    __shared__ float tile[2][64][65];   // double buffer; stride 65: conflict-free
    __shared__ float maskv[256];
    int bx = blockIdx.x;
    int t  = threadIdx.x;
    if (bx < 1024) {
        int i  = bx >> 1;
        int v0 = (bx & 1) << 8;         // v-half base: 0 or 256
        {
            int v = v0 + t;
            maskv[t] = (logits[(size_t)v * VV + i] > 0.0f && v != i) ? 1.0f : 0.0f;
        }
        const float4* src4 = (const float4*)(W1 + ((size_t)i * VV + v0) * HH);
        unsigned short* dst0 = W1t + (size_t)i * (HH * VV) + v0;

        // load sub-tile s (64 v-rows of 64 h) into buffer b
        auto load = [&](int s, int b) {
            #pragma unroll
            for (int jj = 0; jj < 4; ++jj) {
                int c  = jj * 256 + t;         // float4 index in [0, 1024)
                int vr = c >> 4, h4 = c & 15;
                float4 w = src4[s * 1024 + c];
                tile[b][vr][h4 * 4 + 0] = w.x;
                tile[b][vr][h4 * 4 + 1] = w.y;
                tile[b][vr][h4 * 4 + 2] = w.z;
                tile[b][vr][h4 * 4 + 3] = w.w;
            }
        };
        // transpose-store sub-tile s from buffer b (masked, bf16)
        auto store = [&](int s, int b) {
            #pragma unroll
            for (int j = 0; j < 2; ++j) {
                int c = j * 256 + t;
                int h = c >> 3;
                int vr0 = (c & 7) * 8;
                ushort8 o;
                #pragma unroll
                for (int r = 0; r < 8; ++r)
                    o[r] = f2bf_rne(tile[b][vr0 + r][h] * maskv[s * 64 + vr0 + r]);
                *(ushort8*)&dst0[(size_t)h * VV + s * 64 + vr0] = o;
            }
        };

        load(0, 0);
        __syncthreads();                 // tile0 + maskv ready
        #pragma unroll
        for (int s = 0; s < 4; ++s) {
            if (s < 3) load(s + 1, (s + 1) & 1);   // overlaps store(s)
            store(s, s & 1);
            __syncthreads();             // buffer handoff
        }
    } else {
        int idx = (bx - 1024) * 256 + t;           // [0, 262144)
        {   // adj: sigmoid(x) > 0.5  <=>  x > 0 ; zero diagonal
            int v = idx >> 9, u = idx & (VV - 1);
            adj_out[idx] = (logits[idx] > 0.0f && v != u) ? 1.0f : 0.0f;
        }
        {   // X pack: contiguous 32 B read per thread, scattered 16 B write
            int row = idx >> 6;
            int k0  = (idx & 63) << 3;             // 8-float chunk within row
            const float4* s4 = (const float4*)(X + (size_t)row * VV + k0);
            float4 a = s4[0], b = s4[1];
            ushort8 o;
            o[0] = f2bf_rne(a.x); o[1] = f2bf_rne(a.y);
            o[2] = f2bf_rne(a.z); o[3] = f2bf_rne(a.w);
            o[4] = f2bf_rne(b.x); o[5] = f2bf_rne(b.y);
            o[6] = f2bf_rne(b.z); o[7] = f2bf_rne(b.w);
            int rb = row >> 6, mt = (row >> 4) & 3, lnr = row & 15;
            int ks = k0 >> 5, quad = (k0 >> 3) & 3;
            size_t chunk = (((size_t)(rb * 16 + ks) * 4 + mt) << 6) + quad * 16 + lnr;
            *(ushort8*)(Xp + chunk * 8) = o;
        }
    }
}

// ---------------------------------------------------------------- main GEMM
// R3 version restored verbatim (148.8 us, best measured). R4's counted-vmcnt
// ring regressed to 154.3 despite zero bank conflicts -- two independent
// trials (R1, R4) confirm schedule surgery doesn't pay in this shape; the
// kernel sits in a latency equilibrium the 2-drain structure already handles.
// IFUSE=2: each block computes 256 rows x TWO adjacent i's, reusing every
// A-fragment register for both i's MFMAs (-0.5 GB L2 traffic, the R3 win).
__global__ __launch_bounds__(256, 2) void dag_gemm_kernel(
        const unsigned short* __restrict__ Xp,    // packed A frags
        const unsigned short* __restrict__ W1t,   // [V][H][V] bf16 (masked, B^T)
        const float* __restrict__ b1,             // [V][H]
        const float* __restrict__ W2,             // [V][H]
        const float* __restrict__ b2,             // [V]
        float* __restrict__ out)                  // [B][V] final output
{
    __shared__ __align__(16) unsigned short Ws[2][16384];  // 64 KB: [i][h][s2]
    __shared__ float Po[2][256];                           // epilogue gather

    const int t    = threadIdx.x;
    const int wave = t >> 6;
    const int lane = t & 63;
    const int ln   = lane & 15;
    const int quad = lane >> 4;

    const int bx   = blockIdx.x;          // 4096 blocks, i-pair-major
    const int i0   = (bx >> 4) << 1;      // 16 consecutive blocks share i-pair
    const int row0 = (bx & 15) << 8;

    // B-frag fetch: pos = in-half chunk (k/8 units, [0,32)) of row h=nt*16+ln
    auto ldb = [&](int ii, int pos, int nt) -> bf16x8 {
        return *(const bf16x8*)&Ws[ii][(nt * 16 + ln) * 256 + ((pos ^ (ln & 7)) * 8)];
    };

    // wave's packed A stream: 64 KB contiguous, frag(ks,mt) at +(ks*4+mt)*512
    const unsigned short* abase =
        Xp + (size_t)((row0 >> 6) + wave) * (64 * VV) + lane * 8;

    // ---- A prefetch for step 0 (oldest in vmem queue)
    bf16x8 af[2][4];
    #pragma unroll
    for (int mt = 0; mt < 4; ++mt)
        af[0][mt] = *(const bf16x8*)(abase + mt * 512);

    // ---- stage W1t k-half (32 KB per i): lds addr = c*16 (lane-contiguous)
    const unsigned short* wb0 = W1t + (size_t)i0 * (HH * VV);
    const unsigned short* wb1 = W1t + (size_t)(i0 + 1) * (HH * VV);
    auto stage = [&](int kb) {            // kb = 0 (half0) or 32 (half1), in k/8 units
        #pragma unroll
        for (int j = 0; j < 8; ++j) {
            int c = j * 256 + t;          // [0, 2048)
            int h = c >> 5, s2 = c & 31;
            size_t off = (size_t)h * VV + (size_t)(kb + (s2 ^ (h & 7))) * 8;
            gload_lds16(wb0 + off, (char*)&Ws[0][0] + c * 16);
            gload_lds16(wb1 + off, (char*)&Ws[1][0] + c * 16);
        }
    };
    stage(0);
    __syncthreads();   // drains: half0 staged (both i) + af[0] complete

    floatx4 acc[2][4][4];
    #pragma unroll
    for (int ii = 0; ii < 2; ++ii)
        #pragma unroll
        for (int a = 0; a < 4; ++a)
            #pragma unroll
            for (int b = 0; b < 4; ++b)
                acc[ii][a][b] = (floatx4){0.f, 0.f, 0.f, 0.f};

    bf16x8 bq[2][2][4];                   // [step parity][ii][nt]
    #pragma unroll
    for (int ii = 0; ii < 2; ++ii)
        #pragma unroll
        for (int nt = 0; nt < 4; ++nt)
            bq[0][ii][nt] = ldb(ii, quad, nt);

    // ---- K-steps 0..7 (k in [0,256): half0)
    #pragma unroll
    for (int kk = 0; kk < 8; ++kk) {
        #pragma unroll
        for (int mt = 0; mt < 4; ++mt)     // A prefetch for step kk+1
            af[(kk + 1) & 1][mt] =
                *(const bf16x8*)(abase + ((kk + 1) * 4 + mt) * 512);
        if (kk < 7) {                      // B prefetch for step kk+1 (half0)
            #pragma unroll
            for (int ii = 0; ii < 2; ++ii)
                #pragma unroll
                for (int nt = 0; nt < 4; ++nt)
                    bq[(kk + 1) & 1][ii][nt] = ldb(ii, (kk + 1) * 4 + quad, nt);
        }
        #pragma unroll
        for (int ii = 0; ii < 2; ++ii)
            #pragma unroll
            for (int mt = 0; mt < 4; ++mt)
                #pragma unroll
                for (int nt = 0; nt < 4; ++nt)
                    acc[ii][mt][nt] = __builtin_amdgcn_mfma_f32_16x16x32_bf16(
                        af[kk & 1][mt], bq[kk & 1][ii][nt], acc[ii][mt][nt], 0, 0, 0);
    }

    __syncthreads();   // all waves done READING half0 (both i)

    // ---- re-stage half1 (k in [256,512)) into the SAME buffers
    stage(32);
    __syncthreads();   // drains half1 (covered by the other resident block)

    // B frags for step 8 (pos 0 of new half)
    #pragma unroll
    for (int ii = 0; ii < 2; ++ii)
        #pragma unroll
        for (int nt = 0; nt < 4; ++nt)
            bq[0][ii][nt] = ldb(ii, quad, nt);

    // ---- K-steps 8..15 (k in [256,512): half1)
    #pragma unroll
    for (int kk = 8; kk < 16; ++kk) {
        if (kk < 15) {
            #pragma unroll
            for (int mt = 0; mt < 4; ++mt)
                af[(kk + 1) & 1][mt] =
                    *(const bf16x8*)(abase + ((kk + 1) * 4 + mt) * 512);
            #pragma unroll
            for (int ii = 0; ii < 2; ++ii)
                #pragma unroll
                for (int nt = 0; nt < 4; ++nt)
                    bq[(kk + 1) & 1][ii][nt] = ldb(ii, ((kk + 1) - 8) * 4 + quad, nt);
        }
        #pragma unroll
        for (int ii = 0; ii < 2; ++ii)
            #pragma unroll
            for (int mt = 0; mt < 4; ++mt)
                #pragma unroll
                for (int nt = 0; nt < 4; ++nt)
                    acc[ii][mt][nt] = __builtin_amdgcn_mfma_f32_16x16x32_bf16(
                        af[kk & 1][mt], bq[kk & 1][ii][nt], acc[ii][mt][nt], 0, 0, 0);
    }

    // ---- fused epilogue: relu(acc + b1) . W2 + b2, fp32; Po gather is
    //      strictly intra-wave -> no barrier needed before the store.
    float b1v[2][4], w2v[2][4], b2i[2];
    #pragma unroll
    for (int ii = 0; ii < 2; ++ii) {
        #pragma unroll
        for (int nt = 0; nt < 4; ++nt) {
            b1v[ii][nt] = b1[(i0 + ii) * HH + nt * 16 + ln];
            w2v[ii][nt] = W2[(i0 + ii) * HH + nt * 16 + ln];
        }
        b2i[ii] = b2[i0 + ii];
    }
    #pragma unroll
    for (int ii = 0; ii < 2; ++ii) {
        #pragma unroll
        for (int mt = 0; mt < 4; ++mt) {
            #pragma unroll
            for (int r = 0; r < 4; ++r) {
                float p = 0.f;
                #pragma unroll
                for (int nt = 0; nt < 4; ++nt) {
                    float hv = acc[ii][mt][nt][r] + b1v[ii][nt];   // row=quad*4+r, col=nt*16+ln
                    hv = hv > 0.f ? hv : 0.f;
                    p += hv * w2v[ii][nt];
                }
                p += __shfl_xor(p, 8);
                p += __shfl_xor(p, 4);
                p += __shfl_xor(p, 2);
                p += __shfl_xor(p, 1);
                if (ln == 0)
                    Po[ii][wave * 64 + mt * 16 + quad * 4 + r] = p + b2i[ii];
            }
        }
    }
    // direct transposed store: two instrs/lane; writers of each 64 B out
    // line are bx-stride-16 time-adjacent blocks -> L2 write-merges.
    const int row = row0 + wave * 64 + lane;
    out[(size_t)row * VV + i0]     = Po[0][wave * 64 + lane];
    out[(size_t)row * VV + i0 + 1] = Po[1][wave * 64 + lane];
}

// ----------------------------- fallback (no workspace): fp32 vector path
__global__ __launch_bounds__(256) void fallback_kernel(
        const float* __restrict__ X, const float* __restrict__ logits,
        const float* __restrict__ W1, const float* __restrict__ b1,
        const float* __restrict__ W2, const float* __restrict__ b2,
        float* __restrict__ out) {
    __shared__ float Wc[128][64];
    int i   = blockIdx.x & (VV - 1);
    int row = (blockIdx.x >> 9) * 256 + threadIdx.x;
    float acc[64];
    #pragma unroll
    for (int h = 0; h < 64; ++h) acc[h] = 0.f;
    for (int v0 = 0; v0 < VV; v0 += 128) {
        __syncthreads();
        for (int j = 0; j < 32; ++j) {
            int idx = j * 256 + threadIdx.x;
            int vr = idx >> 6, h = idx & 63;
            int v = v0 + vr;
            float m = (logits[(size_t)v * VV + i] > 0.f && v != i) ? 1.f : 0.f;
            Wc[vr][h] = W1[((size_t)i * VV + v) * HH + h] * m;
        }
        __syncthreads();
        for (int vr = 0; vr < 128; ++vr) {
            float xv = X[(size_t)row * VV + v0 + vr];
            #pragma unroll
            for (int h = 0; h < 64; ++h) acc[h] += xv * Wc[vr][h];
        }
    }
    float p = b2[i];
    #pragma unroll
    for (int h = 0; h < 64; ++h) {
        float hv = acc[h] + b1[i * HH + h];
        p += (hv > 0.f ? hv : 0.f) * W2[i * HH + h];
    }
    out[(size_t)row * VV + i] = p;
}

extern "C" void kernel_launch(void* const* d_in, const int* in_sizes, int n_in,
                              void* d_out, int out_size, void* d_ws, size_t ws_size,
                              hipStream_t stream) {
    const float* X      = (const float*)d_in[0];
    const float* logits = (const float*)d_in[1];
    const float* W1     = (const float*)d_in[2];
    const float* b1     = (const float*)d_in[3];
    const float* W2     = (const float*)d_in[4];
    const float* b2     = (const float*)d_in[5];

    float* out     = (float*)d_out;                       // reconstructed [B][V]
    float* adj_out = out + (size_t)BB * VV;               // adj [V][V]

    const size_t xp_bytes  = (size_t)BB * VV * 2;         // 4 MB
    const size_t w1t_bytes = (size_t)VV * HH * VV * 2;    // 32 MB
    const size_t need = xp_bytes + w1t_bytes;

    if (ws_size >= need) {
        unsigned short* Xp  = (unsigned short*)d_ws;
        unsigned short* W1t = (unsigned short*)((char*)d_ws + xp_bytes);
        hipLaunchKernelGGL(prep_fused_kernel, dim3(2048), dim3(256), 0, stream,
                           X, logits, W1, adj_out, Xp, W1t);
        hipLaunchKernelGGL(dag_gemm_kernel, dim3(4096), dim3(256), 0, stream,
                           Xp, W1t, b1, W2, b2, out);
    } else {
        hipLaunchKernelGGL(adj_kernel, dim3((VV * VV) / 256), dim3(256), 0, stream,
                           logits, adj_out);
        hipLaunchKernelGGL(fallback_kernel, dim3(VV * (BB / 256)), dim3(256), 0, stream,
                           X, logits, W1, b1, W2, b2, out);
    }
}